// Round 2
// baseline (482.768 us; speedup 1.0000x reference)
//
#include <hip/hip_runtime.h>
#include <math.h>

// MultilabelCrossEntropyLoss: B=65536 rows, L=1024, X=32 labels (+1 count col).
// loss = mean_b( -log( sum_{j<n_b} prd[b, labels[b,j]] + 1e-6 ) )
//
// R2 strategy: random global gather was transaction-bound (~450 GB/s eff).
// Instead stream each full 4KB row coalesced into LDS (float4, 16B/lane),
// then gather labels from LDS. One wave (64 lanes) per row.

#define NROWS   65536
#define LCOLS   1024
#define TGT_LD  33
#define TOLV    1e-6f
#define INV_B   (1.0f / 65536.0f)
#define WAVES_PER_BLOCK 4

__global__ __launch_bounds__(256)
void mlce_kernel(const float* __restrict__ prd,
                 const int*   __restrict__ tgt,
                 float*       __restrict__ out)
{
    __shared__ float rowbuf[WAVES_PER_BLOCK][LCOLS];   // 16 KB
    __shared__ float partial[WAVES_PER_BLOCK];

    const int w    = threadIdx.x >> 6;
    const int lane = threadIdx.x & 63;
    const int row  = blockIdx.x * WAVES_PER_BLOCK + w;

    // --- stage full row into LDS, coalesced float4 (64 lanes x 4 x 16B = 4KB)
    const float4* __restrict__ src = (const float4*)(prd + row * LCOLS);
    float4* dst = (float4*)rowbuf[w];
    #pragma unroll
    for (int i = 0; i < 4; ++i)
        dst[lane + i * 64] = src[lane + i * 64];

    // --- tgt: 33 ints per row, coalesced
    const int base = row * TGT_LD;
    int lab = 0;
    if (lane < TGT_LD) lab = tgt[base + lane];
    const int n = __shfl(lab, 32, 64);            // broadcast count from lane 32

    __syncthreads();    // orders the wave-private LDS writes before reads

    // --- gather from LDS (single ds_read, ~4-way random bank conflict)
    float v = 0.0f;
    if (lane < 32 && lane < n)
        v = rowbuf[w][lab];

    // --- full-wave reduce (lanes >=32 contribute 0)
    #pragma unroll
    for (int off = 32; off > 0; off >>= 1)
        v += __shfl_xor(v, off, 64);

    if (lane == 0)
        partial[w] = -logf(v + TOLV);
    __syncthreads();

    if (threadIdx.x == 0) {
        const float t = partial[0] + partial[1] + partial[2] + partial[3];
        atomicAdd(out, t * INV_B);                // pre-scaled by 1/B
    }
}

extern "C" void kernel_launch(void* const* d_in, const int* in_sizes, int n_in,
                              void* d_out, int out_size, void* d_ws, size_t ws_size,
                              hipStream_t stream)
{
    const float* prd = (const float*)d_in[0];
    const int*   tgt = (const int*)d_in[1];
    float*       out = (float*)d_out;

    // d_out is re-poisoned to 0xAA before every timed launch: zero it first.
    hipMemsetAsync(out, 0, sizeof(float), stream);

    const int blocks = NROWS / WAVES_PER_BLOCK;   // 16384
    mlce_kernel<<<blocks, 256, 0, stream>>>(prd, tgt, out);
}

// Round 3
// 364.488 us; speedup vs baseline: 1.3245x; 1.3245x over previous
//
#include <hip/hip_runtime.h>
#include <math.h>

// MultilabelCrossEntropyLoss: B=65536 rows, L=1024, X=32 labels (+1 count col).
// loss = mean_b( -log( sum_{j<n_b} prd[b, labels[b,j]] + 1e-6 ) )
//
// R3: R1/R2 were bound by same-address atomicAdd serialization across XCDs
// (~13.5 ns/atomic * 16K atomics ~= 222 us kernel time). Replace with a
// two-stage reduction: per-wave partials to d_ws (plain stores), then a
// single-block finish kernel. Keep R2's coalesced row->LDS staging + gather.

#define NROWS   65536
#define LCOLS   1024
#define TGT_LD  33
#define TOLV    1e-6f
#define INV_B   (1.0f / 65536.0f)

#define WPB            4                    // waves per block
#define BLOCKS         2048
#define TOTAL_WAVES    (BLOCKS * WPB)       // 8192
#define ROWS_PER_WAVE  (NROWS / TOTAL_WAVES) // 8

__global__ __launch_bounds__(256)
void mlce_partial(const float* __restrict__ prd,
                  const int*   __restrict__ tgt,
                  float*       __restrict__ partials)
{
    __shared__ float rowbuf[WPB][LCOLS];    // 16 KB -> 8 blocks/CU possible

    const int w       = threadIdx.x >> 6;
    const int lane    = threadIdx.x & 63;
    const int wave_id = blockIdx.x * WPB + w;

    float acc = 0.0f;

    #pragma unroll 1
    for (int r = 0; r < ROWS_PER_WAVE; ++r) {
        const int row = wave_id * ROWS_PER_WAVE + r;

        // stage full 4KB row into LDS, coalesced float4 (16B/lane)
        const float4* __restrict__ src = (const float4*)(prd + row * LCOLS);
        float4* dst = (float4*)rowbuf[w];
        #pragma unroll
        for (int i = 0; i < 4; ++i)
            dst[lane + i * 64] = src[lane + i * 64];

        // tgt: 33 ints, coalesced; lane 32 holds n
        const int base = row * TGT_LD;
        int lab = 0;
        if (lane < TGT_LD) lab = tgt[base + lane];
        const int n = __shfl(lab, 32, 64);

        __syncthreads();                    // LDS writes visible (per-wave buf)

        float v = 0.0f;
        if (lane < 32 && lane < n)
            v = rowbuf[w][lab];             // LDS gather, ~4-way conflict worst

        #pragma unroll
        for (int off = 32; off > 0; off >>= 1)
            v += __shfl_xor(v, off, 64);

        if (lane == 0)
            acc += -logf(v + TOLV);

        __syncthreads();                    // protect rowbuf before next iter
    }

    if (lane == 0)
        partials[wave_id] = acc;            // plain store, no contention
}

__global__ __launch_bounds__(256)
void mlce_final(const float* __restrict__ partials,
                float*       __restrict__ out)
{
    const int t = threadIdx.x;
    float s = 0.0f;
    #pragma unroll
    for (int i = t; i < TOTAL_WAVES; i += 256)
        s += partials[i];

    #pragma unroll
    for (int off = 32; off > 0; off >>= 1)
        s += __shfl_xor(s, off, 64);

    __shared__ float sm[4];
    const int wid  = t >> 6;
    const int lane = t & 63;
    if (lane == 0) sm[wid] = s;
    __syncthreads();
    if (t == 0)
        out[0] = (sm[0] + sm[1] + sm[2] + sm[3]) * INV_B;
}

extern "C" void kernel_launch(void* const* d_in, const int* in_sizes, int n_in,
                              void* d_out, int out_size, void* d_ws, size_t ws_size,
                              hipStream_t stream)
{
    const float* prd = (const float*)d_in[0];
    const int*   tgt = (const int*)d_in[1];
    float*       out = (float*)d_out;
    float*       ws  = (float*)d_ws;

    mlce_partial<<<BLOCKS, 256, 0, stream>>>(prd, tgt, ws);
    mlce_final<<<1, 256, 0, stream>>>(ws, out);
}